// Round 10
// baseline (352.572 us; speedup 1.0000x reference)
//
#include <hip/hip_runtime.h>
#include <hip/hip_bf16.h>
#include <hip/hip_fp16.h>

#define HID 64
#define NEG_SLOPE 0.2f
#define BLK_E 8192        // edges per block in binning passes
#define EDGE_CAP 6144     // LDS edge cache per bin
#define NDB 16            // blocks for degree sort

typedef _Float16 f16x2 __attribute__((ext_vector_type(2)));

// ============ counting-sort CSR build (no global atomics) ============

__global__ void k_hist2(const int* __restrict__ src, const int* __restrict__ dst,
                        int* __restrict__ histS, int* __restrict__ histD,
                        int E, int NB, int NBLK) {
    __shared__ int hs[512], hd[512];
    int t = threadIdx.x, blk = blockIdx.x;
    for (int b = t; b < NB; b += 1024) { hs[b] = 0; hd[b] = 0; }
    __syncthreads();
    int base = blk * BLK_E;
    #pragma unroll
    for (int k = 0; k < BLK_E / 1024; ++k) {
        int i = base + k * 1024 + t;
        if (i < E) {
            atomicAdd(&hs[src[i] >> 8], 1);
            atomicAdd(&hd[dst[i] >> 8], 1);
        }
    }
    __syncthreads();
    for (int b = t; b < NB; b += 1024) {
        histS[b * NBLK + blk] = hs[b];
        histD[b * NBLK + blk] = hd[b];
    }
}

__global__ void k_binscan(int* __restrict__ histS, int* __restrict__ histD,
                          int* __restrict__ totS, int* __restrict__ totD,
                          int NB, int NBLK) {
    __shared__ int s[256];
    int b = blockIdx.x;
    int* hist = histS; int* tot = totS;
    if (b >= NB) { b -= NB; hist = histD; tot = totD; }
    int t = threadIdx.x;
    int v = (t < NBLK) ? hist[b * NBLK + t] : 0;
    s[t] = v;
    __syncthreads();
    for (int o = 1; o < 256; o <<= 1) {
        int u = (t >= o) ? s[t - o] : 0;
        __syncthreads();
        s[t] += u;
        __syncthreads();
    }
    if (t < NBLK) hist[b * NBLK + t] = s[t] - v;
    if (t == 255) tot[b] = s[255];
}

__global__ void k_binoffset(const int* __restrict__ totS, const int* __restrict__ totD,
                            int* __restrict__ bsS, int* __restrict__ bsD,
                            int NB, int E, int* __restrict__ row_off, int N) {
    __shared__ int s[512];
    int t = threadIdx.x;
    int v = (t < NB) ? totS[t] : 0;
    s[t] = v; __syncthreads();
    for (int o = 1; o < 512; o <<= 1) {
        int u = (t >= o) ? s[t - o] : 0;
        __syncthreads(); s[t] += u; __syncthreads();
    }
    if (t < NB) bsS[t] = s[t] - v;
    if (t == 0) bsS[NB] = E;
    __syncthreads();
    v = (t < NB) ? totD[t] : 0;
    s[t] = v; __syncthreads();
    for (int o = 1; o < 512; o <<= 1) {
        int u = (t >= o) ? s[t - o] : 0;
        __syncthreads(); s[t] += u; __syncthreads();
    }
    if (t < NB) bsD[t] = s[t] - v;
    if (t == 0) { bsD[NB] = E; row_off[N] = E; }
}

__global__ void k_scatter_bins(const int* __restrict__ src, const int* __restrict__ dst,
                               const int* __restrict__ histS, const int* __restrict__ histD,
                               const int* __restrict__ bsS, const int* __restrict__ bsD,
                               unsigned* __restrict__ packS, unsigned* __restrict__ packD,
                               int E, int NB, int NBLK) {
    __shared__ int baseS[512], baseD[512];
    int t = threadIdx.x, blk = blockIdx.x;
    for (int b = t; b < NB; b += 1024) {
        baseS[b] = bsS[b] + histS[b * NBLK + blk];
        baseD[b] = bsD[b] + histD[b * NBLK + blk];
    }
    __syncthreads();
    int base = blk * BLK_E;
    #pragma unroll
    for (int k = 0; k < BLK_E / 1024; ++k) {
        int i = base + k * 1024 + t;
        if (i < E) {
            int sv = src[i], dv = dst[i];
            int pD = atomicAdd(&baseD[dv >> 8], 1);
            packD[pD] = ((unsigned)(dv & 255) << 24) | (unsigned)sv;
            int pS = atomicAdd(&baseS[sv >> 8], 1);
            packS[pS] = (unsigned)(sv & 255);
        }
    }
}

__global__ void k_csr_bin(const unsigned* __restrict__ packD, const int* __restrict__ bsD,
                          int* __restrict__ row_off, float* __restrict__ deg_in,
                          int* __restrict__ csr_src, int N) {
    __shared__ int cnt[256], off[256], cur[256];
    __shared__ unsigned eb[EDGE_CAP];
    int b = blockIdx.x, t = threadIdx.x;
    int lo = bsD[b], hi = bsD[b + 1], ne = hi - lo;
    bool fits = (ne <= EDGE_CAP);
    if (t < 256) cnt[t] = 0;
    __syncthreads();
    for (int i = t; i < ne; i += 1024) {
        unsigned v = packD[lo + i];
        if (fits) eb[i] = v;
        atomicAdd(&cnt[v >> 24], 1);
    }
    __syncthreads();
    if (t < 256) off[t] = cnt[t];
    __syncthreads();
    for (int o = 1; o < 256; o <<= 1) {
        int u = 0;
        if (t < 256 && t >= o) u = off[t - o];
        __syncthreads();
        if (t < 256) off[t] += u;
        __syncthreads();
    }
    if (t < 256) {
        int ex = off[t] - cnt[t];
        cur[t] = lo + ex;
        int node = b * 256 + t;
        if (node < N) {
            row_off[node] = lo + ex;
            deg_in[node] = (float)cnt[t];
        }
    }
    __syncthreads();
    for (int i = t; i < ne; i += 1024) {
        unsigned v = fits ? eb[i] : packD[lo + i];
        int pos = atomicAdd(&cur[v >> 24], 1);
        csr_src[pos] = (int)(v & 0xFFFFFFu);
    }
}

__global__ void k_cnt_bin(const unsigned* __restrict__ packS, const int* __restrict__ bsS,
                          float* __restrict__ deg_out, int N) {
    __shared__ int cnt[256];
    int b = blockIdx.x, t = threadIdx.x;
    int lo = bsS[b], hi = bsS[b + 1];
    if (t < 256) cnt[t] = 0;
    __syncthreads();
    for (int i = lo + t; i < hi; i += 1024) atomicAdd(&cnt[packS[i] & 255], 1);
    __syncthreads();
    if (t < 256) {
        int node = b * 256 + t;
        if (node < N) deg_out[node] = (float)cnt[t];
    }
}

// ============ degree sort (perm only changes scheduling, not any FP result) ============

__global__ void k_deghist(const float* __restrict__ deg_in, int* __restrict__ dhist, int N) {
    __shared__ int h[64];
    int t = threadIdx.x, b = blockIdx.x;
    if (t < 64) h[t] = 0;
    __syncthreads();
    int chunk = (N + NDB - 1) / NDB;
    int lo = b * chunk, hi = lo + chunk; if (hi > N) hi = N;
    for (int i = lo + t; i < hi; i += 1024) {
        int dg = (int)deg_in[i]; if (dg > 63) dg = 63;
        atomicAdd(&h[dg], 1);
    }
    __syncthreads();
    if (t < 64) dhist[t * NDB + b] = h[t];
}

__global__ void k_degscan(int* __restrict__ dhist) {
    __shared__ int s[1024];
    int t = threadIdx.x;
    int v = dhist[t];
    s[t] = v; __syncthreads();
    for (int o = 1; o < 1024; o <<= 1) {
        int u = (t >= o) ? s[t - o] : 0;
        __syncthreads(); s[t] += u; __syncthreads();
    }
    dhist[t] = s[t] - v;
}

__global__ void k_degscatter(const float* __restrict__ deg_in, const int* __restrict__ dhist,
                             int* __restrict__ perm, int N) {
    __shared__ int cur[64];
    int t = threadIdx.x, b = blockIdx.x;
    if (t < 64) cur[t] = dhist[t * NDB + b];
    __syncthreads();
    int chunk = (N + NDB - 1) / NDB;
    int lo = b * chunk, hi = lo + chunk; if (hi > N) hi = N;
    for (int i = lo + t; i < hi; i += 1024) {
        int dg = (int)deg_in[i]; if (dg > 63) dg = 63;
        int p = atomicAdd(&cur[dg], 1);
        perm[p] = i;
    }
}

// ============ model kernels ============

__global__ void k_xfrm1(const float* __restrict__ x, const float* __restrict__ deg_in,
                        const float* __restrict__ deg_out,
                        const float* __restrict__ Wl, const float* __restrict__ bl,
                        const float* __restrict__ Wr, const float* __restrict__ br,
                        __half* __restrict__ A, __half* __restrict__ B, int N) {
    int idx = blockIdx.x * blockDim.x + threadIdx.x;
    if (idx >= N * HID) return;
    int n = idx >> 6, c = idx & 63;
    float h0 = x[n], h1 = deg_in[n], h2 = deg_out[n];
    A[idx] = __float2half(h0 * Wl[c] + h1 * Wl[HID + c] + h2 * Wl[2 * HID + c] + bl[c]);
    B[idx] = __float2half(h0 * Wr[c] + h1 * Wr[HID + c] + h2 * Wr[2 * HID + c] + br[c]);
}

struct H8 { f16x2 h[8]; };

__device__ __forceinline__ f16x2 bch2(unsigned u) {
    return __builtin_bit_cast(f16x2, u);
}

__device__ __forceinline__ H8 ldrow(const uint4* __restrict__ T, size_t base) {
    uint4 r0 = T[base], r1 = T[base + 1];
    H8 o;
    o.h[0] = bch2(r0.x); o.h[1] = bch2(r0.y); o.h[2] = bch2(r0.z); o.h[3] = bch2(r0.w);
    o.h[4] = bch2(r1.x); o.h[5] = bch2(r1.y); o.h[6] = bch2(r1.z); o.h[7] = bch2(r1.w);
    return o;
}

// 16-channel partial logit: a^T leakyrelu(a_row + xr), pk-f16 math + fp32 dot
__device__ __forceinline__ float logit16(const H8& a, const H8& x,
                                         const float* __restrict__ awf, f16x2 ns2) {
    float t = 0.0f;
    #pragma unroll
    for (int j = 0; j < 8; ++j) {
        f16x2 s = a.h[j] + x.h[j];
        f16x2 l = __builtin_elementwise_max(s, ns2 * s);
        t = fmaf((float)l.x, awf[2 * j], t);
        t = fmaf((float)l.y, awf[2 * j + 1], t);
    }
    return t;
}

__device__ __forceinline__ void accum16(float* __restrict__ acc, const H8& a, float w) {
    #pragma unroll
    for (int j = 0; j < 8; ++j) {
        acc[2 * j]     = fmaf((float)a.h[j].x, w, acc[2 * j]);
        acc[2 * j + 1] = fmaf((float)a.h[j].y, w, acc[2 * j + 1]);
    }
}

// Fused GATv2 layer: 4 lanes per dst node (16 ch each), descending-degree order,
// software-pipelined batch-4 loop (prefetch next batch before computing current),
// zero-weight padding for tails, online softmax, no atomics.
template <bool TANH>
__global__ void k_gat_fused(const int* __restrict__ csr_src, const int* __restrict__ row_off,
                            const int* __restrict__ perm,
                            const __half* __restrict__ Ah, const __half* __restrict__ Bh,
                            const float* __restrict__ aw, const float* __restrict__ bias,
                            float* __restrict__ out, int N) {
    int tid = blockIdx.x * blockDim.x + threadIdx.x;
    int r = tid >> 2;
    int gl = threadIdx.x & 3;
    if (r >= N) return;
    int d = perm[N - 1 - r];   // descending degree: heavy rows dispatched first

    const uint4* A16 = (const uint4*)Ah;
    const uint4* B16 = (const uint4*)Bh;
    f16x2 ns2;
    ns2.x = (_Float16)NEG_SLOPE; ns2.y = (_Float16)NEG_SLOPE;

    float awf[16];
    {
        const float4* a4 = (const float4*)aw;
        #pragma unroll
        for (int j = 0; j < 4; ++j) {
            float4 v = a4[gl * 4 + j];
            awf[4 * j] = v.x; awf[4 * j + 1] = v.y; awf[4 * j + 2] = v.z; awf[4 * j + 3] = v.w;
        }
    }

    size_t rowbase = (size_t)d * 8 + gl * 2;
    H8 xh = ldrow(B16, rowbase);
    H8 as = ldrow(A16, rowbase);

    // self loop seeds online-softmax state
    float t = logit16(as, xh, awf, ns2);
    t += __shfl_xor(t, 1); t += __shfl_xor(t, 2);
    float m = t, denom = 1.0f;
    float acc[16];
    #pragma unroll
    for (int j = 0; j < 8; ++j) {
        acc[2 * j] = (float)as.h[j].x;
        acc[2 * j + 1] = (float)as.h[j].y;
    }

    int lo = row_off[d], hi = row_off[d + 1];
    if (lo < hi) {
        int k = lo;
        // prologue: load batch at k (indices clamped; padded lanes masked later)
        int ka = k + 1 < hi ? k + 1 : hi - 1;
        int kb = k + 2 < hi ? k + 2 : hi - 1;
        int kc = k + 3 < hi ? k + 3 : hi - 1;
        int s0 = csr_src[k], s1 = csr_src[ka], s2 = csr_src[kb], s3 = csr_src[kc];
        H8 c0 = ldrow(A16, (size_t)s0 * 8 + gl * 2);
        H8 c1 = ldrow(A16, (size_t)s1 * 8 + gl * 2);
        H8 c2 = ldrow(A16, (size_t)s2 * 8 + gl * 2);
        H8 c3 = ldrow(A16, (size_t)s3 * 8 + gl * 2);
        while (true) {
            int kn = k + 4;
            bool more = kn < hi;
            H8 n0, n1, n2, n3;
            if (more) {
                // prefetch next batch BEFORE computing current: loads overlap compute
                int ja = kn + 1 < hi ? kn + 1 : hi - 1;
                int jb = kn + 2 < hi ? kn + 2 : hi - 1;
                int jc = kn + 3 < hi ? kn + 3 : hi - 1;
                int u0 = csr_src[kn], u1 = csr_src[ja], u2 = csr_src[jb], u3 = csr_src[jc];
                n0 = ldrow(A16, (size_t)u0 * 8 + gl * 2);
                n1 = ldrow(A16, (size_t)u1 * 8 + gl * 2);
                n2 = ldrow(A16, (size_t)u2 * 8 + gl * 2);
                n3 = ldrow(A16, (size_t)u3 * 8 + gl * 2);
            }
            float t0 = logit16(c0, xh, awf, ns2);
            float t1 = logit16(c1, xh, awf, ns2);
            float t2 = logit16(c2, xh, awf, ns2);
            float t3 = logit16(c3, xh, awf, ns2);
            t0 += __shfl_xor(t0, 1); t1 += __shfl_xor(t1, 1);
            t2 += __shfl_xor(t2, 1); t3 += __shfl_xor(t3, 1);
            t0 += __shfl_xor(t0, 2); t1 += __shfl_xor(t1, 2);
            t2 += __shfl_xor(t2, 2); t3 += __shfl_xor(t3, 2);
            // mask padded slots: exp(-1e30 - m) == 0, max unaffected
            if (k + 1 >= hi) t1 = -1e30f;
            if (k + 2 >= hi) t2 = -1e30f;
            if (k + 3 >= hi) t3 = -1e30f;
            float mx = fmaxf(fmaxf(t0, t1), fmaxf(t2, t3));
            if (mx > m) {
                float sc = __expf(m - mx);
                denom *= sc;
                #pragma unroll
                for (int j = 0; j < 16; ++j) acc[j] *= sc;
                m = mx;
            }
            float w0 = __expf(t0 - m), w1 = __expf(t1 - m);
            float w2 = __expf(t2 - m), w3 = __expf(t3 - m);
            denom += (w0 + w1) + (w2 + w3);
            accum16(acc, c0, w0);
            accum16(acc, c1, w1);
            accum16(acc, c2, w2);
            accum16(acc, c3, w3);
            if (!more) break;
            c0 = n0; c1 = n1; c2 = n2; c3 = n3;
            k = kn;
        }
    }

    float inv = 1.0f / denom;
    const float4* b4 = (const float4*)bias;
    float4* o4 = (float4*)out;
    #pragma unroll
    for (int j = 0; j < 4; ++j) {
        float4 bv = b4[gl * 4 + j];
        float4 o;
        o.x = acc[4 * j] * inv + bv.x;
        o.y = acc[4 * j + 1] * inv + bv.y;
        o.z = acc[4 * j + 2] * inv + bv.z;
        o.w = acc[4 * j + 3] * inv + bv.w;
        if (TANH) { o.x = tanhf(o.x); o.y = tanhf(o.y); o.z = tanhf(o.z); o.w = tanhf(o.w); }
        o4[(size_t)d * 16 + gl * 4 + j] = o;
    }
}

// layer-2 transforms, LDS-tiled: block = 512 threads (8 waves) x 64 nodes. fp16 output.
__global__ __launch_bounds__(512) void k_xfrm2(
        const float* __restrict__ H,
        const float* __restrict__ Wl, const float* __restrict__ bl,
        const float* __restrict__ Wr, const float* __restrict__ br,
        __half* __restrict__ A, __half* __restrict__ B, int N) {
    __shared__ float wls[4096];       // [kk][c]
    __shared__ float wrs[4096];
    __shared__ float hst[64 * 66];    // transposed: [kk][node], pad 66
    int t = threadIdx.x;
    int base = blockIdx.x * 64;

    ((float4*)wls)[t * 2]     = ((const float4*)Wl)[t * 2];
    ((float4*)wls)[t * 2 + 1] = ((const float4*)Wl)[t * 2 + 1];
    ((float4*)wrs)[t * 2]     = ((const float4*)Wr)[t * 2];
    ((float4*)wrs)[t * 2 + 1] = ((const float4*)Wr)[t * 2 + 1];

    #pragma unroll
    for (int u = 0; u < 2; ++u) {
        int j = t * 2 + u;
        int nd = j >> 4, c4 = j & 15;
        int node = base + nd;
        float4 hv = (node < N) ? ((const float4*)H)[(size_t)node * 16 + c4]
                               : make_float4(0.f, 0.f, 0.f, 0.f);
        hst[(c4 * 4 + 0) * 66 + nd] = hv.x;
        hst[(c4 * 4 + 1) * 66 + nd] = hv.y;
        hst[(c4 * 4 + 2) * 66 + nd] = hv.z;
        hst[(c4 * 4 + 3) * 66 + nd] = hv.w;
    }
    __syncthreads();

    int w = t >> 6, l = t & 63;
    float acL[8] = {0, 0, 0, 0, 0, 0, 0, 0};
    float acR[8] = {0, 0, 0, 0, 0, 0, 0, 0};
    #pragma unroll 4
    for (int kk = 0; kk < 64; ++kk) {
        float hv = hst[kk * 66 + l];
        const float4* wl4 = (const float4*)&wls[kk * 64 + w * 8];
        const float4* wr4 = (const float4*)&wrs[kk * 64 + w * 8];
        float4 w0 = wl4[0], w1 = wl4[1];
        float4 r0 = wr4[0], r1 = wr4[1];
        acL[0] = fmaf(hv, w0.x, acL[0]); acL[1] = fmaf(hv, w0.y, acL[1]);
        acL[2] = fmaf(hv, w0.z, acL[2]); acL[3] = fmaf(hv, w0.w, acL[3]);
        acL[4] = fmaf(hv, w1.x, acL[4]); acL[5] = fmaf(hv, w1.y, acL[5]);
        acL[6] = fmaf(hv, w1.z, acL[6]); acL[7] = fmaf(hv, w1.w, acL[7]);
        acR[0] = fmaf(hv, r0.x, acR[0]); acR[1] = fmaf(hv, r0.y, acR[1]);
        acR[2] = fmaf(hv, r0.z, acR[2]); acR[3] = fmaf(hv, r0.w, acR[3]);
        acR[4] = fmaf(hv, r1.x, acR[4]); acR[5] = fmaf(hv, r1.y, acR[5]);
        acR[6] = fmaf(hv, r1.z, acR[6]); acR[7] = fmaf(hv, r1.w, acR[7]);
    }

    int node = base + l;
    if (node < N) {
        float4 bl0 = ((const float4*)bl)[w * 2], bl1 = ((const float4*)bl)[w * 2 + 1];
        float4 br0 = ((const float4*)br)[w * 2], br1 = ((const float4*)br)[w * 2 + 1];
        __half2* A2 = (__half2*)A;
        __half2* B2 = (__half2*)B;
        size_t bo = (size_t)node * 32 + w * 4;
        A2[bo + 0] = __floats2half2_rn(acL[0] + bl0.x, acL[1] + bl0.y);
        A2[bo + 1] = __floats2half2_rn(acL[2] + bl0.z, acL[3] + bl0.w);
        A2[bo + 2] = __floats2half2_rn(acL[4] + bl1.x, acL[5] + bl1.y);
        A2[bo + 3] = __floats2half2_rn(acL[6] + bl1.z, acL[7] + bl1.w);
        B2[bo + 0] = __floats2half2_rn(acR[0] + br0.x, acR[1] + br0.y);
        B2[bo + 1] = __floats2half2_rn(acR[2] + br0.z, acR[3] + br0.w);
        B2[bo + 2] = __floats2half2_rn(acR[4] + br1.x, acR[5] + br1.y);
        B2[bo + 3] = __floats2half2_rn(acR[6] + br1.z, acR[7] + br1.w);
    }
}

// fused pool + final linear: one wave per graph; binary-search bounds from sorted batch;
// 4-row-unrolled channel max; in-wave shuffle reduce for the 64x2 matvec.
__global__ void k_pool_final(const float* __restrict__ C, const float* __restrict__ b2,
                             const int* __restrict__ batch,
                             const float* __restrict__ W3, const float* __restrict__ b3,
                             float* __restrict__ out, int N, int G) {
    int w = (int)((blockIdx.x * (size_t)blockDim.x + threadIdx.x) >> 6);
    int lane = threadIdx.x & 63;
    if (w >= G) return;
    // lower_bound(batch, w) and lower_bound(batch, w+1) — uniform across the wave
    int lo = 0, hi = N;
    while (lo < hi) { int mid = (lo + hi) >> 1; if (batch[mid] < w) lo = mid + 1; else hi = mid; }
    int s0 = lo;
    hi = N;
    while (lo < hi) { int mid = (lo + hi) >> 1; if (batch[mid] < w + 1) lo = mid + 1; else hi = mid; }
    int e0 = lo;

    float acc = -INFINITY;
    int i = s0;
    for (; i + 3 < e0; i += 4) {
        float v0 = C[(size_t)i * HID + lane];
        float v1 = C[(size_t)(i + 1) * HID + lane];
        float v2 = C[(size_t)(i + 2) * HID + lane];
        float v3 = C[(size_t)(i + 3) * HID + lane];
        acc = fmaxf(acc, fmaxf(fmaxf(v0, v1), fmaxf(v2, v3)));
    }
    for (; i < e0; ++i) acc = fmaxf(acc, C[(size_t)i * HID + lane]);
    float v = acc + b2[lane];

    float p0 = v * W3[lane * 2];
    float p1 = v * W3[lane * 2 + 1];
    #pragma unroll
    for (int o = 32; o; o >>= 1) { p0 += __shfl_xor(p0, o); p1 += __shfl_xor(p1, o); }
    if (lane == 0) {
        out[(size_t)w * 2]     = p0 + b3[0];
        out[(size_t)w * 2 + 1] = p1 + b3[1];
    }
}

extern "C" void kernel_launch(void* const* d_in, const int* in_sizes, int n_in,
                              void* d_out, int out_size, void* d_ws, size_t ws_size,
                              hipStream_t stream) {
    const float* x     = (const float*)d_in[0];
    const int*   ei    = (const int*)d_in[1];
    const int*   batch = (const int*)d_in[2];
    const float* Wl1 = (const float*)d_in[3];
    const float* bl1 = (const float*)d_in[4];
    const float* Wr1 = (const float*)d_in[5];
    const float* br1 = (const float*)d_in[6];
    const float* a1  = (const float*)d_in[7];
    const float* b1  = (const float*)d_in[8];
    const float* Wl2 = (const float*)d_in[9];
    const float* bl2 = (const float*)d_in[10];
    const float* Wr2 = (const float*)d_in[11];
    const float* br2 = (const float*)d_in[12];
    const float* a2  = (const float*)d_in[13];
    const float* b2  = (const float*)d_in[14];
    const float* W3  = (const float*)d_in[15];
    const float* b3  = (const float*)d_in[16];

    const int N = in_sizes[0];          // 100000
    const int E = in_sizes[1] / 2;      // 1600000
    const int G = out_size / 2;         // 1000
    const int NB = (N + 255) >> 8;
    const int NBLK = (E + BLK_E - 1) / BLK_E;

    // ---- workspace layout ----
    float* ws = (float*)d_ws;
    size_t off = 0;
    float*  C  = ws + off; off += (size_t)N * HID;          // sort temporaries overlay here
    __half* Ah = (__half*)(ws + off); off += (size_t)N * HID / 2;
    __half* Bh = (__half*)(ws + off); off += (size_t)N * HID / 2;
    int*   row_off = (int*)(ws + off); off += N + 1;
    int*   csr_src = (int*)(ws + off); off += E;
    float* deg_in  = ws + off; off += N;
    float* deg_out = ws + off; off += N;
    int*   perm    = (int*)(ws + off); off += N;
    int*   dhist   = (int*)(ws + off); off += 1024;
    int*   bsS  = (int*)(ws + off); off += NB + 1;
    int*   bsD  = (int*)(ws + off); off += NB + 1;
    int*   totS = (int*)(ws + off); off += NB;
    int*   totD = (int*)(ws + off); off += NB;

    unsigned* packD = (unsigned*)C;
    unsigned* packS = packD + E;
    int* histS = (int*)(packS + E);
    int* histD = histS + (size_t)NB * NBLK;

    const int* src  = ei;
    const int* dstp = ei + E;

    const int BT = 256;
    dim3 blk(BT);
    int grid_nodeC = (N * HID + BT - 1) / BT;
    int grid_g4    = (int)(((size_t)N * 4 + BT - 1) / BT);
    int grid_x2    = (N + 63) / 64;

    // ---- CSR build via counting sort (no global atomics) ----
    k_hist2<<<NBLK, 1024, 0, stream>>>(src, dstp, histS, histD, E, NB, NBLK);
    k_binscan<<<2 * NB, 256, 0, stream>>>(histS, histD, totS, totD, NB, NBLK);
    k_binoffset<<<1, 512, 0, stream>>>(totS, totD, bsS, bsD, NB, E, row_off, N);
    k_scatter_bins<<<NBLK, 1024, 0, stream>>>(src, dstp, histS, histD, bsS, bsD,
                                              packS, packD, E, NB, NBLK);
    k_csr_bin<<<NB, 1024, 0, stream>>>(packD, bsD, row_off, deg_in, csr_src, N);
    k_cnt_bin<<<NB, 1024, 0, stream>>>(packS, bsS, deg_out, N);

    // ---- degree-sorted node permutation (scheduling only) ----
    k_deghist<<<NDB, 1024, 0, stream>>>(deg_in, dhist, N);
    k_degscan<<<1, 1024, 0, stream>>>(dhist);
    k_degscatter<<<NDB, 1024, 0, stream>>>(deg_in, dhist, perm, N);

    // ---- layer 1 ----
    k_xfrm1<<<grid_nodeC, blk, 0, stream>>>(x, deg_in, deg_out, Wl1, bl1, Wr1, br1, Ah, Bh, N);
    k_gat_fused<true><<<grid_g4, blk, 0, stream>>>(csr_src, row_off, perm, Ah, Bh, a1, b1, C, N);

    // ---- layer 2 ----
    k_xfrm2<<<grid_x2, 512, 0, stream>>>(C, Wl2, bl2, Wr2, br2, Ah, Bh, N);
    k_gat_fused<false><<<grid_g4, blk, 0, stream>>>(csr_src, row_off, perm, Ah, Bh, a2, b2, C, N);

    // ---- fused pool + final linear ----
    k_pool_final<<<(G * 64 + BT - 1) / BT, blk, 0, stream>>>(C, b2, batch, W3, b3,
                                                             (float*)d_out, N, G);
}

// Round 11
// 232.559 us; speedup vs baseline: 1.5161x; 1.5161x over previous
//
#include <hip/hip_runtime.h>
#include <hip/hip_bf16.h>
#include <hip/hip_fp16.h>

#define HID 64
#define NEG_SLOPE 0.2f
#define BLK_E 4096        // edges per block in binning passes (391 blocks -> better occupancy)
#define EDGE_CAP 6144     // LDS edge cache per bin
#define NDB 16            // blocks for degree sort

typedef _Float16 f16x2 __attribute__((ext_vector_type(2)));

// ============ counting-sort CSR build (no global atomics) ============

__global__ void k_hist2(const int* __restrict__ src, const int* __restrict__ dst,
                        int* __restrict__ histS, int* __restrict__ histD,
                        int E, int NB, int NBLK) {
    __shared__ int hs[512], hd[512];
    int t = threadIdx.x, blk = blockIdx.x;
    for (int b = t; b < NB; b += 1024) { hs[b] = 0; hd[b] = 0; }
    __syncthreads();
    int base = blk * BLK_E;
    #pragma unroll
    for (int k = 0; k < BLK_E / 1024; ++k) {
        int i = base + k * 1024 + t;
        if (i < E) {
            atomicAdd(&hs[src[i] >> 8], 1);
            atomicAdd(&hd[dst[i] >> 8], 1);
        }
    }
    __syncthreads();
    for (int b = t; b < NB; b += 1024) {
        histS[b * NBLK + blk] = hs[b];
        histD[b * NBLK + blk] = hd[b];
    }
}

// per-bin scan over blocks (NBLK <= 512)
__global__ void k_binscan(int* __restrict__ histS, int* __restrict__ histD,
                          int* __restrict__ totS, int* __restrict__ totD,
                          int NB, int NBLK) {
    __shared__ int s[512];
    int b = blockIdx.x;
    int* hist = histS; int* tot = totS;
    if (b >= NB) { b -= NB; hist = histD; tot = totD; }
    int t = threadIdx.x;
    int v = (t < NBLK) ? hist[b * NBLK + t] : 0;
    s[t] = v;
    __syncthreads();
    for (int o = 1; o < 512; o <<= 1) {
        int u = (t >= o) ? s[t - o] : 0;
        __syncthreads();
        s[t] += u;
        __syncthreads();
    }
    if (t < NBLK) hist[b * NBLK + t] = s[t] - v;
    if (t == 511) tot[b] = s[511];
}

__global__ void k_binoffset(const int* __restrict__ totS, const int* __restrict__ totD,
                            int* __restrict__ bsS, int* __restrict__ bsD,
                            int NB, int E, int* __restrict__ row_off, int N) {
    __shared__ int s[512];
    int t = threadIdx.x;
    int v = (t < NB) ? totS[t] : 0;
    s[t] = v; __syncthreads();
    for (int o = 1; o < 512; o <<= 1) {
        int u = (t >= o) ? s[t - o] : 0;
        __syncthreads(); s[t] += u; __syncthreads();
    }
    if (t < NB) bsS[t] = s[t] - v;
    if (t == 0) bsS[NB] = E;
    __syncthreads();
    v = (t < NB) ? totD[t] : 0;
    s[t] = v; __syncthreads();
    for (int o = 1; o < 512; o <<= 1) {
        int u = (t >= o) ? s[t - o] : 0;
        __syncthreads(); s[t] += u; __syncthreads();
    }
    if (t < NB) bsD[t] = s[t] - v;
    if (t == 0) { bsD[NB] = E; row_off[N] = E; }
}

__global__ void k_scatter_bins(const int* __restrict__ src, const int* __restrict__ dst,
                               const int* __restrict__ histS, const int* __restrict__ histD,
                               const int* __restrict__ bsS, const int* __restrict__ bsD,
                               unsigned* __restrict__ packS, unsigned* __restrict__ packD,
                               int E, int NB, int NBLK) {
    __shared__ int baseS[512], baseD[512];
    int t = threadIdx.x, blk = blockIdx.x;
    for (int b = t; b < NB; b += 1024) {
        baseS[b] = bsS[b] + histS[b * NBLK + blk];
        baseD[b] = bsD[b] + histD[b * NBLK + blk];
    }
    __syncthreads();
    int base = blk * BLK_E;
    #pragma unroll
    for (int k = 0; k < BLK_E / 1024; ++k) {
        int i = base + k * 1024 + t;
        if (i < E) {
            int sv = src[i], dv = dst[i];
            int pD = atomicAdd(&baseD[dv >> 8], 1);
            packD[pD] = ((unsigned)(dv & 255) << 24) | (unsigned)sv;
            int pS = atomicAdd(&baseS[sv >> 8], 1);
            packS[pS] = (unsigned)(sv & 255);
        }
    }
}

__global__ void k_csr_bin(const unsigned* __restrict__ packD, const int* __restrict__ bsD,
                          int* __restrict__ row_off, float* __restrict__ deg_in,
                          int* __restrict__ csr_src, int N) {
    __shared__ int cnt[256], off[256], cur[256];
    __shared__ unsigned eb[EDGE_CAP];
    int b = blockIdx.x, t = threadIdx.x;
    int lo = bsD[b], hi = bsD[b + 1], ne = hi - lo;
    bool fits = (ne <= EDGE_CAP);
    if (t < 256) cnt[t] = 0;
    __syncthreads();
    for (int i = t; i < ne; i += 1024) {
        unsigned v = packD[lo + i];
        if (fits) eb[i] = v;
        atomicAdd(&cnt[v >> 24], 1);
    }
    __syncthreads();
    if (t < 256) off[t] = cnt[t];
    __syncthreads();
    for (int o = 1; o < 256; o <<= 1) {
        int u = 0;
        if (t < 256 && t >= o) u = off[t - o];
        __syncthreads();
        if (t < 256) off[t] += u;
        __syncthreads();
    }
    if (t < 256) {
        int ex = off[t] - cnt[t];
        cur[t] = lo + ex;
        int node = b * 256 + t;
        if (node < N) {
            row_off[node] = lo + ex;
            deg_in[node] = (float)cnt[t];
        }
    }
    __syncthreads();
    for (int i = t; i < ne; i += 1024) {
        unsigned v = fits ? eb[i] : packD[lo + i];
        int pos = atomicAdd(&cur[v >> 24], 1);
        csr_src[pos] = (int)(v & 0xFFFFFFu);
    }
}

__global__ void k_cnt_bin(const unsigned* __restrict__ packS, const int* __restrict__ bsS,
                          float* __restrict__ deg_out, int N) {
    __shared__ int cnt[256];
    int b = blockIdx.x, t = threadIdx.x;
    int lo = bsS[b], hi = bsS[b + 1];
    if (t < 256) cnt[t] = 0;
    __syncthreads();
    for (int i = lo + t; i < hi; i += 1024) atomicAdd(&cnt[packS[i] & 255], 1);
    __syncthreads();
    if (t < 256) {
        int node = b * 256 + t;
        if (node < N) deg_out[node] = (float)cnt[t];
    }
}

// ============ degree sort (perm only changes scheduling, not any FP result) ============

__global__ void k_deghist(const float* __restrict__ deg_in, int* __restrict__ dhist, int N) {
    __shared__ int h[64];
    int t = threadIdx.x, b = blockIdx.x;
    if (t < 64) h[t] = 0;
    __syncthreads();
    int chunk = (N + NDB - 1) / NDB;
    int lo = b * chunk, hi = lo + chunk; if (hi > N) hi = N;
    for (int i = lo + t; i < hi; i += 1024) {
        int dg = (int)deg_in[i]; if (dg > 63) dg = 63;
        atomicAdd(&h[dg], 1);
    }
    __syncthreads();
    if (t < 64) dhist[t * NDB + b] = h[t];
}

__global__ void k_degscan(int* __restrict__ dhist) {
    __shared__ int s[1024];
    int t = threadIdx.x;
    int v = dhist[t];
    s[t] = v; __syncthreads();
    for (int o = 1; o < 1024; o <<= 1) {
        int u = (t >= o) ? s[t - o] : 0;
        __syncthreads(); s[t] += u; __syncthreads();
    }
    dhist[t] = s[t] - v;
}

__global__ void k_degscatter(const float* __restrict__ deg_in, const int* __restrict__ dhist,
                             int* __restrict__ perm, int N) {
    __shared__ int cur[64];
    int t = threadIdx.x, b = blockIdx.x;
    if (t < 64) cur[t] = dhist[t * NDB + b];
    __syncthreads();
    int chunk = (N + NDB - 1) / NDB;
    int lo = b * chunk, hi = lo + chunk; if (hi > N) hi = N;
    for (int i = lo + t; i < hi; i += 1024) {
        int dg = (int)deg_in[i]; if (dg > 63) dg = 63;
        int p = atomicAdd(&cur[dg], 1);
        perm[p] = i;
    }
}

// ============ model kernels ============

__global__ void k_xfrm1(const float* __restrict__ x, const float* __restrict__ deg_in,
                        const float* __restrict__ deg_out,
                        const float* __restrict__ Wl, const float* __restrict__ bl,
                        const float* __restrict__ Wr, const float* __restrict__ br,
                        __half* __restrict__ A, __half* __restrict__ B, int N) {
    int idx = blockIdx.x * blockDim.x + threadIdx.x;
    if (idx >= N * HID) return;
    int n = idx >> 6, c = idx & 63;
    float h0 = x[n], h1 = deg_in[n], h2 = deg_out[n];
    A[idx] = __float2half(h0 * Wl[c] + h1 * Wl[HID + c] + h2 * Wl[2 * HID + c] + bl[c]);
    B[idx] = __float2half(h0 * Wr[c] + h1 * Wr[HID + c] + h2 * Wr[2 * HID + c] + br[c]);
}

struct H8 { f16x2 h[8]; };

__device__ __forceinline__ f16x2 bch2(unsigned u) {
    return __builtin_bit_cast(f16x2, u);
}

__device__ __forceinline__ H8 ldrow(const uint4* __restrict__ T, size_t base) {
    uint4 r0 = T[base], r1 = T[base + 1];
    H8 o;
    o.h[0] = bch2(r0.x); o.h[1] = bch2(r0.y); o.h[2] = bch2(r0.z); o.h[3] = bch2(r0.w);
    o.h[4] = bch2(r1.x); o.h[5] = bch2(r1.y); o.h[6] = bch2(r1.z); o.h[7] = bch2(r1.w);
    return o;
}

// 16-channel partial logit: a^T leakyrelu(a_row + xr), pk-f16 math + fp32 dot
__device__ __forceinline__ float logit16(const H8& a, const H8& x,
                                         const float* __restrict__ awf, f16x2 ns2) {
    float t = 0.0f;
    #pragma unroll
    for (int j = 0; j < 8; ++j) {
        f16x2 s = a.h[j] + x.h[j];
        f16x2 l = __builtin_elementwise_max(s, ns2 * s);
        t = fmaf((float)l.x, awf[2 * j], t);
        t = fmaf((float)l.y, awf[2 * j + 1], t);
    }
    return t;
}

__device__ __forceinline__ void accum16(float* __restrict__ acc, const H8& a, float w) {
    #pragma unroll
    for (int j = 0; j < 8; ++j) {
        acc[2 * j]     = fmaf((float)a.h[j].x, w, acc[2 * j]);
        acc[2 * j + 1] = fmaf((float)a.h[j].y, w, acc[2 * j + 1]);
    }
}

// Fused GATv2 layer: 4 lanes per dst node (16 ch each), descending-degree order,
// batch-4 edge unroll for MLP, online softmax, no atomics. (round-9 body: no
// software pipeline — the explicit prefetch variant spilled to scratch.)
template <bool TANH>
__global__ void k_gat_fused(const int* __restrict__ csr_src, const int* __restrict__ row_off,
                            const int* __restrict__ perm,
                            const __half* __restrict__ Ah, const __half* __restrict__ Bh,
                            const float* __restrict__ aw, const float* __restrict__ bias,
                            float* __restrict__ out, int N) {
    int tid = blockIdx.x * blockDim.x + threadIdx.x;
    int r = tid >> 2;
    int gl = threadIdx.x & 3;
    if (r >= N) return;
    int d = perm[N - 1 - r];   // descending degree: heavy rows dispatched first

    const uint4* A16 = (const uint4*)Ah;
    const uint4* B16 = (const uint4*)Bh;
    f16x2 ns2;
    ns2.x = (_Float16)NEG_SLOPE; ns2.y = (_Float16)NEG_SLOPE;

    float awf[16];
    {
        const float4* a4 = (const float4*)aw;
        #pragma unroll
        for (int j = 0; j < 4; ++j) {
            float4 v = a4[gl * 4 + j];
            awf[4 * j] = v.x; awf[4 * j + 1] = v.y; awf[4 * j + 2] = v.z; awf[4 * j + 3] = v.w;
        }
    }

    size_t rowbase = (size_t)d * 8 + gl * 2;
    H8 xh = ldrow(B16, rowbase);
    H8 as = ldrow(A16, rowbase);

    // self loop seeds online-softmax state
    float t = logit16(as, xh, awf, ns2);
    t += __shfl_xor(t, 1); t += __shfl_xor(t, 2);
    float m = t, denom = 1.0f;
    float acc[16];
    #pragma unroll
    for (int j = 0; j < 8; ++j) {
        acc[2 * j] = (float)as.h[j].x;
        acc[2 * j + 1] = (float)as.h[j].y;
    }

    int lo = row_off[d], hi = row_off[d + 1];
    int k = lo;
    // batch-4: 8 row-loads in flight, one rescale check per 4 edges
    for (; k + 3 < hi; k += 4) {
        int s0 = csr_src[k], s1 = csr_src[k + 1], s2 = csr_src[k + 2], s3 = csr_src[k + 3];
        H8 a0 = ldrow(A16, (size_t)s0 * 8 + gl * 2);
        H8 a1 = ldrow(A16, (size_t)s1 * 8 + gl * 2);
        H8 a2 = ldrow(A16, (size_t)s2 * 8 + gl * 2);
        H8 a3 = ldrow(A16, (size_t)s3 * 8 + gl * 2);
        float t0 = logit16(a0, xh, awf, ns2);
        float t1 = logit16(a1, xh, awf, ns2);
        float t2 = logit16(a2, xh, awf, ns2);
        float t3 = logit16(a3, xh, awf, ns2);
        t0 += __shfl_xor(t0, 1); t1 += __shfl_xor(t1, 1);
        t2 += __shfl_xor(t2, 1); t3 += __shfl_xor(t3, 1);
        t0 += __shfl_xor(t0, 2); t1 += __shfl_xor(t1, 2);
        t2 += __shfl_xor(t2, 2); t3 += __shfl_xor(t3, 2);
        float mx = fmaxf(fmaxf(t0, t1), fmaxf(t2, t3));
        if (mx > m) {
            float sc = __expf(m - mx);
            denom *= sc;
            #pragma unroll
            for (int j = 0; j < 16; ++j) acc[j] *= sc;
            m = mx;
        }
        float w0 = __expf(t0 - m), w1 = __expf(t1 - m);
        float w2 = __expf(t2 - m), w3 = __expf(t3 - m);
        denom += (w0 + w1) + (w2 + w3);
        accum16(acc, a0, w0);
        accum16(acc, a1, w1);
        accum16(acc, a2, w2);
        accum16(acc, a3, w3);
    }
    // tail (<=3 edges)
    for (; k < hi; ++k) {
        int s0 = csr_src[k];
        H8 a0 = ldrow(A16, (size_t)s0 * 8 + gl * 2);
        float t0 = logit16(a0, xh, awf, ns2);
        t0 += __shfl_xor(t0, 1); t0 += __shfl_xor(t0, 2);
        if (t0 > m) {
            float sc = __expf(m - t0);
            denom *= sc;
            #pragma unroll
            for (int j = 0; j < 16; ++j) acc[j] *= sc;
            m = t0;
        }
        float w0 = __expf(t0 - m);
        denom += w0;
        accum16(acc, a0, w0);
    }

    float inv = 1.0f / denom;
    const float4* b4 = (const float4*)bias;
    float4* o4 = (float4*)out;
    #pragma unroll
    for (int j = 0; j < 4; ++j) {
        float4 bv = b4[gl * 4 + j];
        float4 o;
        o.x = acc[4 * j] * inv + bv.x;
        o.y = acc[4 * j + 1] * inv + bv.y;
        o.z = acc[4 * j + 2] * inv + bv.z;
        o.w = acc[4 * j + 3] * inv + bv.w;
        if (TANH) { o.x = tanhf(o.x); o.y = tanhf(o.y); o.z = tanhf(o.z); o.w = tanhf(o.w); }
        o4[(size_t)d * 16 + gl * 4 + j] = o;
    }
}

// layer-2 transforms, LDS-tiled: block = 512 threads (8 waves) x 64 nodes. fp16 output.
__global__ __launch_bounds__(512) void k_xfrm2(
        const float* __restrict__ H,
        const float* __restrict__ Wl, const float* __restrict__ bl,
        const float* __restrict__ Wr, const float* __restrict__ br,
        __half* __restrict__ A, __half* __restrict__ B, int N) {
    __shared__ float wls[4096];       // [kk][c]
    __shared__ float wrs[4096];
    __shared__ float hst[64 * 66];    // transposed: [kk][node], pad 66
    int t = threadIdx.x;
    int base = blockIdx.x * 64;

    ((float4*)wls)[t * 2]     = ((const float4*)Wl)[t * 2];
    ((float4*)wls)[t * 2 + 1] = ((const float4*)Wl)[t * 2 + 1];
    ((float4*)wrs)[t * 2]     = ((const float4*)Wr)[t * 2];
    ((float4*)wrs)[t * 2 + 1] = ((const float4*)Wr)[t * 2 + 1];

    #pragma unroll
    for (int u = 0; u < 2; ++u) {
        int j = t * 2 + u;
        int nd = j >> 4, c4 = j & 15;
        int node = base + nd;
        float4 hv = (node < N) ? ((const float4*)H)[(size_t)node * 16 + c4]
                               : make_float4(0.f, 0.f, 0.f, 0.f);
        hst[(c4 * 4 + 0) * 66 + nd] = hv.x;
        hst[(c4 * 4 + 1) * 66 + nd] = hv.y;
        hst[(c4 * 4 + 2) * 66 + nd] = hv.z;
        hst[(c4 * 4 + 3) * 66 + nd] = hv.w;
    }
    __syncthreads();

    int w = t >> 6, l = t & 63;
    float acL[8] = {0, 0, 0, 0, 0, 0, 0, 0};
    float acR[8] = {0, 0, 0, 0, 0, 0, 0, 0};
    #pragma unroll 4
    for (int kk = 0; kk < 64; ++kk) {
        float hv = hst[kk * 66 + l];
        const float4* wl4 = (const float4*)&wls[kk * 64 + w * 8];
        const float4* wr4 = (const float4*)&wrs[kk * 64 + w * 8];
        float4 w0 = wl4[0], w1 = wl4[1];
        float4 r0 = wr4[0], r1 = wr4[1];
        acL[0] = fmaf(hv, w0.x, acL[0]); acL[1] = fmaf(hv, w0.y, acL[1]);
        acL[2] = fmaf(hv, w0.z, acL[2]); acL[3] = fmaf(hv, w0.w, acL[3]);
        acL[4] = fmaf(hv, w1.x, acL[4]); acL[5] = fmaf(hv, w1.y, acL[5]);
        acL[6] = fmaf(hv, w1.z, acL[6]); acL[7] = fmaf(hv, w1.w, acL[7]);
        acR[0] = fmaf(hv, r0.x, acR[0]); acR[1] = fmaf(hv, r0.y, acR[1]);
        acR[2] = fmaf(hv, r0.z, acR[2]); acR[3] = fmaf(hv, r0.w, acR[3]);
        acR[4] = fmaf(hv, r1.x, acR[4]); acR[5] = fmaf(hv, r1.y, acR[5]);
        acR[6] = fmaf(hv, r1.z, acR[6]); acR[7] = fmaf(hv, r1.w, acR[7]);
    }

    int node = base + l;
    if (node < N) {
        float4 bl0 = ((const float4*)bl)[w * 2], bl1 = ((const float4*)bl)[w * 2 + 1];
        float4 br0 = ((const float4*)br)[w * 2], br1 = ((const float4*)br)[w * 2 + 1];
        __half2* A2 = (__half2*)A;
        __half2* B2 = (__half2*)B;
        size_t bo = (size_t)node * 32 + w * 4;
        A2[bo + 0] = __floats2half2_rn(acL[0] + bl0.x, acL[1] + bl0.y);
        A2[bo + 1] = __floats2half2_rn(acL[2] + bl0.z, acL[3] + bl0.w);
        A2[bo + 2] = __floats2half2_rn(acL[4] + bl1.x, acL[5] + bl1.y);
        A2[bo + 3] = __floats2half2_rn(acL[6] + bl1.z, acL[7] + bl1.w);
        B2[bo + 0] = __floats2half2_rn(acR[0] + br0.x, acR[1] + br0.y);
        B2[bo + 1] = __floats2half2_rn(acR[2] + br0.z, acR[3] + br0.w);
        B2[bo + 2] = __floats2half2_rn(acR[4] + br1.x, acR[5] + br1.y);
        B2[bo + 3] = __floats2half2_rn(acR[6] + br1.z, acR[7] + br1.w);
    }
}

// fused pool + final linear: one wave per graph; binary-search bounds from sorted batch;
// 4-row-unrolled channel max; in-wave shuffle reduce for the 64x2 matvec.
__global__ void k_pool_final(const float* __restrict__ C, const float* __restrict__ b2,
                             const int* __restrict__ batch,
                             const float* __restrict__ W3, const float* __restrict__ b3,
                             float* __restrict__ out, int N, int G) {
    int w = (int)((blockIdx.x * (size_t)blockDim.x + threadIdx.x) >> 6);
    int lane = threadIdx.x & 63;
    if (w >= G) return;
    int lo = 0, hi = N;
    while (lo < hi) { int mid = (lo + hi) >> 1; if (batch[mid] < w) lo = mid + 1; else hi = mid; }
    int s0 = lo;
    hi = N;
    while (lo < hi) { int mid = (lo + hi) >> 1; if (batch[mid] < w + 1) lo = mid + 1; else hi = mid; }
    int e0 = lo;

    float acc = -INFINITY;
    int i = s0;
    for (; i + 3 < e0; i += 4) {
        float v0 = C[(size_t)i * HID + lane];
        float v1 = C[(size_t)(i + 1) * HID + lane];
        float v2 = C[(size_t)(i + 2) * HID + lane];
        float v3 = C[(size_t)(i + 3) * HID + lane];
        acc = fmaxf(acc, fmaxf(fmaxf(v0, v1), fmaxf(v2, v3)));
    }
    for (; i < e0; ++i) acc = fmaxf(acc, C[(size_t)i * HID + lane]);
    float v = acc + b2[lane];

    float p0 = v * W3[lane * 2];
    float p1 = v * W3[lane * 2 + 1];
    #pragma unroll
    for (int o = 32; o; o >>= 1) { p0 += __shfl_xor(p0, o); p1 += __shfl_xor(p1, o); }
    if (lane == 0) {
        out[(size_t)w * 2]     = p0 + b3[0];
        out[(size_t)w * 2 + 1] = p1 + b3[1];
    }
}

extern "C" void kernel_launch(void* const* d_in, const int* in_sizes, int n_in,
                              void* d_out, int out_size, void* d_ws, size_t ws_size,
                              hipStream_t stream) {
    const float* x     = (const float*)d_in[0];
    const int*   ei    = (const int*)d_in[1];
    const int*   batch = (const int*)d_in[2];
    const float* Wl1 = (const float*)d_in[3];
    const float* bl1 = (const float*)d_in[4];
    const float* Wr1 = (const float*)d_in[5];
    const float* br1 = (const float*)d_in[6];
    const float* a1  = (const float*)d_in[7];
    const float* b1  = (const float*)d_in[8];
    const float* Wl2 = (const float*)d_in[9];
    const float* bl2 = (const float*)d_in[10];
    const float* Wr2 = (const float*)d_in[11];
    const float* br2 = (const float*)d_in[12];
    const float* a2  = (const float*)d_in[13];
    const float* b2  = (const float*)d_in[14];
    const float* W3  = (const float*)d_in[15];
    const float* b3  = (const float*)d_in[16];

    const int N = in_sizes[0];          // 100000
    const int E = in_sizes[1] / 2;      // 1600000
    const int G = out_size / 2;         // 1000
    const int NB = (N + 255) >> 8;                 // 391 node bins
    const int NBLK = (E + BLK_E - 1) / BLK_E;      // 391 edge blocks

    // ---- workspace layout ----
    float* ws = (float*)d_ws;
    size_t off = 0;
    float*  C  = ws + off; off += (size_t)N * HID;          // sort temporaries overlay here
    __half* Ah = (__half*)(ws + off); off += (size_t)N * HID / 2;
    __half* Bh = (__half*)(ws + off); off += (size_t)N * HID / 2;
    int*   row_off = (int*)(ws + off); off += N + 1;
    int*   csr_src = (int*)(ws + off); off += E;
    float* deg_in  = ws + off; off += N;
    float* deg_out = ws + off; off += N;
    int*   perm    = (int*)(ws + off); off += N;
    int*   dhist   = (int*)(ws + off); off += 1024;
    int*   bsS  = (int*)(ws + off); off += NB + 1;
    int*   bsD  = (int*)(ws + off); off += NB + 1;
    int*   totS = (int*)(ws + off); off += NB;
    int*   totD = (int*)(ws + off); off += NB;

    unsigned* packD = (unsigned*)C;
    unsigned* packS = packD + E;
    int* histS = (int*)(packS + E);
    int* histD = histS + (size_t)NB * NBLK;

    const int* src  = ei;
    const int* dstp = ei + E;

    const int BT = 256;
    dim3 blk(BT);
    int grid_nodeC = (N * HID + BT - 1) / BT;
    int grid_g4    = (int)(((size_t)N * 4 + BT - 1) / BT);
    int grid_x2    = (N + 63) / 64;

    // ---- CSR build via counting sort (no global atomics) ----
    k_hist2<<<NBLK, 1024, 0, stream>>>(src, dstp, histS, histD, E, NB, NBLK);
    k_binscan<<<2 * NB, 512, 0, stream>>>(histS, histD, totS, totD, NB, NBLK);
    k_binoffset<<<1, 512, 0, stream>>>(totS, totD, bsS, bsD, NB, E, row_off, N);
    k_scatter_bins<<<NBLK, 1024, 0, stream>>>(src, dstp, histS, histD, bsS, bsD,
                                              packS, packD, E, NB, NBLK);
    k_csr_bin<<<NB, 1024, 0, stream>>>(packD, bsD, row_off, deg_in, csr_src, N);
    k_cnt_bin<<<NB, 1024, 0, stream>>>(packS, bsS, deg_out, N);

    // ---- degree-sorted node permutation (scheduling only) ----
    k_deghist<<<NDB, 1024, 0, stream>>>(deg_in, dhist, N);
    k_degscan<<<1, 1024, 0, stream>>>(dhist);
    k_degscatter<<<NDB, 1024, 0, stream>>>(deg_in, dhist, perm, N);

    // ---- layer 1 ----
    k_xfrm1<<<grid_nodeC, blk, 0, stream>>>(x, deg_in, deg_out, Wl1, bl1, Wr1, br1, Ah, Bh, N);
    k_gat_fused<true><<<grid_g4, blk, 0, stream>>>(csr_src, row_off, perm, Ah, Bh, a1, b1, C, N);

    // ---- layer 2 ----
    k_xfrm2<<<grid_x2, 512, 0, stream>>>(C, Wl2, bl2, Wr2, br2, Ah, Bh, N);
    k_gat_fused<false><<<grid_g4, blk, 0, stream>>>(csr_src, row_off, perm, Ah, Bh, a2, b2, C, N);

    // ---- fused pool + final linear ----
    k_pool_final<<<(G * 64 + BT - 1) / BT, blk, 0, stream>>>(C, b2, batch, W3, b3,
                                                             (float*)d_out, N, G);
}

// Round 12
// 218.141 us; speedup vs baseline: 1.6163x; 1.0661x over previous
//
#include <hip/hip_runtime.h>
#include <hip/hip_bf16.h>
#include <hip/hip_fp16.h>

#define HID 64
#define NEG_SLOPE 0.2f
#define BLK_E 4096        // edges per block in binning passes
#define EDGE_CAP 6144     // LDS edge cache per bin
#define NDB 16            // blocks for degree sort

typedef _Float16 f16x2 __attribute__((ext_vector_type(2)));

// ============ counting-sort CSR build (no global atomics) ============

__global__ void k_hist2(const int* __restrict__ src, const int* __restrict__ dst,
                        int* __restrict__ histS, int* __restrict__ histD,
                        int E, int NB, int NBLK) {
    __shared__ int hs[512], hd[512];
    int t = threadIdx.x, blk = blockIdx.x;
    for (int b = t; b < NB; b += 1024) { hs[b] = 0; hd[b] = 0; }
    __syncthreads();
    int base = blk * BLK_E;
    #pragma unroll
    for (int k = 0; k < BLK_E / 1024; ++k) {
        int i = base + k * 1024 + t;
        if (i < E) {
            atomicAdd(&hs[src[i] >> 8], 1);
            atomicAdd(&hd[dst[i] >> 8], 1);
        }
    }
    __syncthreads();
    for (int b = t; b < NB; b += 1024) {
        histS[b * NBLK + blk] = hs[b];
        histD[b * NBLK + blk] = hd[b];
    }
}

// per-bin scan over blocks (NBLK <= 512)
__global__ void k_binscan(int* __restrict__ histS, int* __restrict__ histD,
                          int* __restrict__ totS, int* __restrict__ totD,
                          int NB, int NBLK) {
    __shared__ int s[512];
    int b = blockIdx.x;
    int* hist = histS; int* tot = totS;
    if (b >= NB) { b -= NB; hist = histD; tot = totD; }
    int t = threadIdx.x;
    int v = (t < NBLK) ? hist[b * NBLK + t] : 0;
    s[t] = v;
    __syncthreads();
    for (int o = 1; o < 512; o <<= 1) {
        int u = (t >= o) ? s[t - o] : 0;
        __syncthreads();
        s[t] += u;
        __syncthreads();
    }
    if (t < NBLK) hist[b * NBLK + t] = s[t] - v;
    if (t == 511) tot[b] = s[511];
}

__global__ void k_binoffset(const int* __restrict__ totS, const int* __restrict__ totD,
                            int* __restrict__ bsS, int* __restrict__ bsD,
                            int NB, int E, int* __restrict__ row_off, int N) {
    __shared__ int s[512];
    int t = threadIdx.x;
    int v = (t < NB) ? totS[t] : 0;
    s[t] = v; __syncthreads();
    for (int o = 1; o < 512; o <<= 1) {
        int u = (t >= o) ? s[t - o] : 0;
        __syncthreads(); s[t] += u; __syncthreads();
    }
    if (t < NB) bsS[t] = s[t] - v;
    if (t == 0) bsS[NB] = E;
    __syncthreads();
    v = (t < NB) ? totD[t] : 0;
    s[t] = v; __syncthreads();
    for (int o = 1; o < 512; o <<= 1) {
        int u = (t >= o) ? s[t - o] : 0;
        __syncthreads(); s[t] += u; __syncthreads();
    }
    if (t < NB) bsD[t] = s[t] - v;
    if (t == 0) { bsD[NB] = E; row_off[N] = E; }
}

__global__ void k_scatter_bins(const int* __restrict__ src, const int* __restrict__ dst,
                               const int* __restrict__ histS, const int* __restrict__ histD,
                               const int* __restrict__ bsS, const int* __restrict__ bsD,
                               unsigned* __restrict__ packS, unsigned* __restrict__ packD,
                               int E, int NB, int NBLK) {
    __shared__ int baseS[512], baseD[512];
    int t = threadIdx.x, blk = blockIdx.x;
    for (int b = t; b < NB; b += 1024) {
        baseS[b] = bsS[b] + histS[b * NBLK + blk];
        baseD[b] = bsD[b] + histD[b * NBLK + blk];
    }
    __syncthreads();
    int base = blk * BLK_E;
    #pragma unroll
    for (int k = 0; k < BLK_E / 1024; ++k) {
        int i = base + k * 1024 + t;
        if (i < E) {
            int sv = src[i], dv = dst[i];
            int pD = atomicAdd(&baseD[dv >> 8], 1);
            packD[pD] = ((unsigned)(dv & 255) << 24) | (unsigned)sv;
            int pS = atomicAdd(&baseS[sv >> 8], 1);
            packS[pS] = (unsigned)(sv & 255);
        }
    }
}

// fused: per-bin CSR finalize (deg_in, row_off, sorted csr_src) + src-side count
// (deg_out) + layer-1 transforms (A,B fp16) for the bin's 256 nodes.
__global__ void k_csr_bin_fused(const unsigned* __restrict__ packD, const int* __restrict__ bsD,
                                const unsigned* __restrict__ packS, const int* __restrict__ bsS,
                                int* __restrict__ row_off, float* __restrict__ deg_in,
                                int* __restrict__ csr_src,
                                const float* __restrict__ x,
                                const float* __restrict__ Wl, const float* __restrict__ bl,
                                const float* __restrict__ Wr, const float* __restrict__ br,
                                __half* __restrict__ A, __half* __restrict__ B, int N) {
    __shared__ int cnt[256], off[256], cur[256], cntS[256];
    __shared__ unsigned eb[EDGE_CAP];
    int b = blockIdx.x, t = threadIdx.x;
    int lo = bsD[b], hi = bsD[b + 1], ne = hi - lo;
    bool fits = (ne <= EDGE_CAP);
    if (t < 256) { cnt[t] = 0; cntS[t] = 0; }
    __syncthreads();
    for (int i = t; i < ne; i += 1024) {
        unsigned v = packD[lo + i];
        if (fits) eb[i] = v;
        atomicAdd(&cnt[v >> 24], 1);
    }
    int loS = bsS[b], hiS = bsS[b + 1];
    for (int i = loS + t; i < hiS; i += 1024) atomicAdd(&cntS[packS[i] & 255], 1);
    __syncthreads();
    if (t < 256) off[t] = cnt[t];
    __syncthreads();
    for (int o = 1; o < 256; o <<= 1) {
        int u = 0;
        if (t < 256 && t >= o) u = off[t - o];
        __syncthreads();
        if (t < 256) off[t] += u;
        __syncthreads();
    }
    if (t < 256) {
        int ex = off[t] - cnt[t];
        cur[t] = lo + ex;
        int node = b * 256 + t;
        if (node < N) {
            row_off[node] = lo + ex;
            deg_in[node] = (float)cnt[t];
        }
    }
    __syncthreads();
    for (int i = t; i < ne; i += 1024) {
        unsigned v = fits ? eb[i] : packD[lo + i];
        int pos = atomicAdd(&cur[v >> 24], 1);
        csr_src[pos] = (int)(v & 0xFFFFFFu);
    }
    // ---- fused layer-1 transform for this bin's nodes ----
    // thread t: node = b*256 + (t>>2), channels [(t&3)*16, +16)
    int nd = b * 256 + (t >> 2);
    if (nd < N) {
        float h0 = x[nd];
        float h1 = (float)cnt[t >> 2];
        float h2 = (float)cntS[t >> 2];
        int c0 = (t & 3) * 16;
        unsigned ua[4], ub[4];
        #pragma unroll
        for (int p = 0; p < 2; ++p) {
            #pragma unroll
            for (int q = 0; q < 4; ++q) {
                int c = c0 + p * 8 + q * 2;
                float a0 = h0 * Wl[c]     + h1 * Wl[64 + c]     + h2 * Wl[128 + c]     + bl[c];
                float a1 = h0 * Wl[c + 1] + h1 * Wl[64 + c + 1] + h2 * Wl[128 + c + 1] + bl[c + 1];
                float b0 = h0 * Wr[c]     + h1 * Wr[64 + c]     + h2 * Wr[128 + c]     + br[c];
                float b1 = h0 * Wr[c + 1] + h1 * Wr[64 + c + 1] + h2 * Wr[128 + c + 1] + br[c + 1];
                f16x2 pa; pa.x = (_Float16)a0; pa.y = (_Float16)a1;
                f16x2 pb; pb.x = (_Float16)b0; pb.y = (_Float16)b1;
                if (q < 4) { ua[q] = __builtin_bit_cast(unsigned, pa); ub[q] = __builtin_bit_cast(unsigned, pb); }
            }
            uint4 sa = make_uint4(ua[0], ua[1], ua[2], ua[3]);
            uint4 sb = make_uint4(ub[0], ub[1], ub[2], ub[3]);
            ((uint4*)A)[(size_t)nd * 8 + (t & 3) * 2 + p] = sa;
            ((uint4*)B)[(size_t)nd * 8 + (t & 3) * 2 + p] = sb;
        }
    }
}

// ============ degree sort (perm only changes scheduling, not any FP result) ============

__global__ void k_deghist(const float* __restrict__ deg_in, int* __restrict__ dhist, int N) {
    __shared__ int h[64];
    int t = threadIdx.x, b = blockIdx.x;
    if (t < 64) h[t] = 0;
    __syncthreads();
    int chunk = (N + NDB - 1) / NDB;
    int lo = b * chunk, hi = lo + chunk; if (hi > N) hi = N;
    for (int i = lo + t; i < hi; i += 1024) {
        int dg = (int)deg_in[i]; if (dg > 63) dg = 63;
        atomicAdd(&h[dg], 1);
    }
    __syncthreads();
    if (t < 64) dhist[t * NDB + b] = h[t];
}

__global__ void k_degscan(int* __restrict__ dhist) {
    __shared__ int s[1024];
    int t = threadIdx.x;
    int v = dhist[t];
    s[t] = v; __syncthreads();
    for (int o = 1; o < 1024; o <<= 1) {
        int u = (t >= o) ? s[t - o] : 0;
        __syncthreads(); s[t] += u; __syncthreads();
    }
    dhist[t] = s[t] - v;
}

__global__ void k_degscatter(const float* __restrict__ deg_in, const int* __restrict__ dhist,
                             int* __restrict__ perm, int N) {
    __shared__ int cur[64];
    int t = threadIdx.x, b = blockIdx.x;
    if (t < 64) cur[t] = dhist[t * NDB + b];
    __syncthreads();
    int chunk = (N + NDB - 1) / NDB;
    int lo = b * chunk, hi = lo + chunk; if (hi > N) hi = N;
    for (int i = lo + t; i < hi; i += 1024) {
        int dg = (int)deg_in[i]; if (dg > 63) dg = 63;
        int p = atomicAdd(&cur[dg], 1);
        perm[p] = i;
    }
}

// ============ fused GAT layer: 8 lanes per dst node (8 ch each) ============

struct H4 { f16x2 h[4]; };

__device__ __forceinline__ f16x2 bch2(unsigned u) {
    return __builtin_bit_cast(f16x2, u);
}

__device__ __forceinline__ H4 ld4(const uint4* __restrict__ T, size_t idx) {
    uint4 r = T[idx];
    H4 o;
    o.h[0] = bch2(r.x); o.h[1] = bch2(r.y); o.h[2] = bch2(r.z); o.h[3] = bch2(r.w);
    return o;
}

// 8-channel partial logit
__device__ __forceinline__ float logit8(const H4& a, const H4& x,
                                        const float* __restrict__ awf, f16x2 ns2) {
    float t = 0.0f;
    #pragma unroll
    for (int j = 0; j < 4; ++j) {
        f16x2 s = a.h[j] + x.h[j];
        f16x2 l = __builtin_elementwise_max(s, ns2 * s);
        t = fmaf((float)l.x, awf[2 * j], t);
        t = fmaf((float)l.y, awf[2 * j + 1], t);
    }
    return t;
}

__device__ __forceinline__ void accum8(float* __restrict__ acc, const H4& a, float w) {
    #pragma unroll
    for (int j = 0; j < 4; ++j) {
        acc[2 * j]     = fmaf((float)a.h[j].x, w, acc[2 * j]);
        acc[2 * j + 1] = fmaf((float)a.h[j].y, w, acc[2 * j + 1]);
    }
}

template <typename OUT, bool TANH>
__global__ void k_gat_fused(const int* __restrict__ csr_src, const int* __restrict__ row_off,
                            const int* __restrict__ perm,
                            const __half* __restrict__ Ah, const __half* __restrict__ Bh,
                            const float* __restrict__ aw, const float* __restrict__ bias,
                            OUT* __restrict__ out, int N) {
    int tid = blockIdx.x * blockDim.x + threadIdx.x;
    int r = tid >> 3;
    int gl = threadIdx.x & 7;
    if (r >= N) return;
    int d = perm[N - 1 - r];   // descending degree

    const uint4* A16 = (const uint4*)Ah;
    const uint4* B16 = (const uint4*)Bh;
    f16x2 ns2;
    ns2.x = (_Float16)NEG_SLOPE; ns2.y = (_Float16)NEG_SLOPE;

    float awf[8], bw[8];
    {
        const float4* a4 = (const float4*)aw;
        const float4* b4 = (const float4*)bias;
        #pragma unroll
        for (int j = 0; j < 2; ++j) {
            float4 v = a4[gl * 2 + j];
            awf[4 * j] = v.x; awf[4 * j + 1] = v.y; awf[4 * j + 2] = v.z; awf[4 * j + 3] = v.w;
            float4 u = b4[gl * 2 + j];
            bw[4 * j] = u.x; bw[4 * j + 1] = u.y; bw[4 * j + 2] = u.z; bw[4 * j + 3] = u.w;
        }
    }

    size_t rowbase = (size_t)d * 8 + gl;
    H4 xh = ld4(B16, rowbase);
    H4 as = ld4(A16, rowbase);

    // self loop seeds online-softmax state
    float t = logit8(as, xh, awf, ns2);
    t += __shfl_xor(t, 1); t += __shfl_xor(t, 2); t += __shfl_xor(t, 4);
    float m = t, denom = 1.0f;
    float acc[8];
    #pragma unroll
    for (int j = 0; j < 4; ++j) {
        acc[2 * j] = (float)as.h[j].x;
        acc[2 * j + 1] = (float)as.h[j].y;
    }

    int lo = row_off[d], hi = row_off[d + 1];
    int k = lo;
    for (; k + 3 < hi; k += 4) {
        int s0 = csr_src[k], s1 = csr_src[k + 1], s2 = csr_src[k + 2], s3 = csr_src[k + 3];
        H4 a0 = ld4(A16, (size_t)s0 * 8 + gl);
        H4 a1 = ld4(A16, (size_t)s1 * 8 + gl);
        H4 a2 = ld4(A16, (size_t)s2 * 8 + gl);
        H4 a3 = ld4(A16, (size_t)s3 * 8 + gl);
        float t0 = logit8(a0, xh, awf, ns2);
        float t1 = logit8(a1, xh, awf, ns2);
        float t2 = logit8(a2, xh, awf, ns2);
        float t3 = logit8(a3, xh, awf, ns2);
        t0 += __shfl_xor(t0, 1); t1 += __shfl_xor(t1, 1);
        t2 += __shfl_xor(t2, 1); t3 += __shfl_xor(t3, 1);
        t0 += __shfl_xor(t0, 2); t1 += __shfl_xor(t1, 2);
        t2 += __shfl_xor(t2, 2); t3 += __shfl_xor(t3, 2);
        t0 += __shfl_xor(t0, 4); t1 += __shfl_xor(t1, 4);
        t2 += __shfl_xor(t2, 4); t3 += __shfl_xor(t3, 4);
        float mx = fmaxf(fmaxf(t0, t1), fmaxf(t2, t3));
        if (mx > m) {
            float sc = __expf(m - mx);
            denom *= sc;
            #pragma unroll
            for (int j = 0; j < 8; ++j) acc[j] *= sc;
            m = mx;
        }
        float w0 = __expf(t0 - m), w1 = __expf(t1 - m);
        float w2 = __expf(t2 - m), w3 = __expf(t3 - m);
        denom += (w0 + w1) + (w2 + w3);
        accum8(acc, a0, w0);
        accum8(acc, a1, w1);
        accum8(acc, a2, w2);
        accum8(acc, a3, w3);
    }
    for (; k < hi; ++k) {
        int s0 = csr_src[k];
        H4 a0 = ld4(A16, (size_t)s0 * 8 + gl);
        float t0 = logit8(a0, xh, awf, ns2);
        t0 += __shfl_xor(t0, 1); t0 += __shfl_xor(t0, 2); t0 += __shfl_xor(t0, 4);
        if (t0 > m) {
            float sc = __expf(m - t0);
            denom *= sc;
            #pragma unroll
            for (int j = 0; j < 8; ++j) acc[j] *= sc;
            m = t0;
        }
        float w0 = __expf(t0 - m);
        denom += w0;
        accum8(acc, a0, w0);
    }

    float inv = 1.0f / denom;
    float v[8];
    #pragma unroll
    for (int j = 0; j < 8; ++j) {
        v[j] = acc[j] * inv + bw[j];
        if (TANH) v[j] = tanhf(v[j]);
    }
    if constexpr (sizeof(OUT) == 2) {
        unsigned u[4];
        #pragma unroll
        for (int j = 0; j < 4; ++j) {
            f16x2 p; p.x = (_Float16)v[2 * j]; p.y = (_Float16)v[2 * j + 1];
            u[j] = __builtin_bit_cast(unsigned, p);
        }
        ((uint4*)out)[(size_t)d * 8 + gl] = make_uint4(u[0], u[1], u[2], u[3]);
    } else {
        float4* o4 = (float4*)out;
        o4[(size_t)d * 16 + gl * 2]     = make_float4(v[0], v[1], v[2], v[3]);
        o4[(size_t)d * 16 + gl * 2 + 1] = make_float4(v[4], v[5], v[6], v[7]);
    }
}

// layer-2 transforms, LDS-tiled: block = 512 threads (8 waves) x 64 nodes.
// fp16 input (layer-1 C), fp16 output tables.
__global__ __launch_bounds__(512) void k_xfrm2(
        const __half* __restrict__ H,
        const float* __restrict__ Wl, const float* __restrict__ bl,
        const float* __restrict__ Wr, const float* __restrict__ br,
        __half* __restrict__ A, __half* __restrict__ B, int N) {
    __shared__ float wls[4096];       // [kk][c]
    __shared__ float wrs[4096];
    __shared__ float hst[64 * 66];    // transposed: [kk][node], pad 66
    int t = threadIdx.x;
    int base = blockIdx.x * 64;

    ((float4*)wls)[t * 2]     = ((const float4*)Wl)[t * 2];
    ((float4*)wls)[t * 2 + 1] = ((const float4*)Wl)[t * 2 + 1];
    ((float4*)wrs)[t * 2]     = ((const float4*)Wr)[t * 2];
    ((float4*)wrs)[t * 2 + 1] = ((const float4*)Wr)[t * 2 + 1];

    // stage h tile (fp16), transposed to [kk][node]
    {
        int nd = t >> 3, q = t & 7;       // one uint4 (8 halves) per thread
        int node = base + nd;
        uint4 hv = (node < N) ? ((const uint4*)H)[(size_t)node * 8 + q]
                              : make_uint4(0, 0, 0, 0);
        f16x2 p0 = bch2(hv.x), p1 = bch2(hv.y), p2 = bch2(hv.z), p3 = bch2(hv.w);
        int c = q * 8;
        hst[(c + 0) * 66 + nd] = (float)p0.x;
        hst[(c + 1) * 66 + nd] = (float)p0.y;
        hst[(c + 2) * 66 + nd] = (float)p1.x;
        hst[(c + 3) * 66 + nd] = (float)p1.y;
        hst[(c + 4) * 66 + nd] = (float)p2.x;
        hst[(c + 5) * 66 + nd] = (float)p2.y;
        hst[(c + 6) * 66 + nd] = (float)p3.x;
        hst[(c + 7) * 66 + nd] = (float)p3.y;
    }
    __syncthreads();

    int w = t >> 6, l = t & 63;
    float acL[8] = {0, 0, 0, 0, 0, 0, 0, 0};
    float acR[8] = {0, 0, 0, 0, 0, 0, 0, 0};
    #pragma unroll 4
    for (int kk = 0; kk < 64; ++kk) {
        float hv = hst[kk * 66 + l];
        const float4* wl4 = (const float4*)&wls[kk * 64 + w * 8];
        const float4* wr4 = (const float4*)&wrs[kk * 64 + w * 8];
        float4 w0 = wl4[0], w1 = wl4[1];
        float4 r0 = wr4[0], r1 = wr4[1];
        acL[0] = fmaf(hv, w0.x, acL[0]); acL[1] = fmaf(hv, w0.y, acL[1]);
        acL[2] = fmaf(hv, w0.z, acL[2]); acL[3] = fmaf(hv, w0.w, acL[3]);
        acL[4] = fmaf(hv, w1.x, acL[4]); acL[5] = fmaf(hv, w1.y, acL[5]);
        acL[6] = fmaf(hv, w1.z, acL[6]); acL[7] = fmaf(hv, w1.w, acL[7]);
        acR[0] = fmaf(hv, r0.x, acR[0]); acR[1] = fmaf(hv, r0.y, acR[1]);
        acR[2] = fmaf(hv, r0.z, acR[2]); acR[3] = fmaf(hv, r0.w, acR[3]);
        acR[4] = fmaf(hv, r1.x, acR[4]); acR[5] = fmaf(hv, r1.y, acR[5]);
        acR[6] = fmaf(hv, r1.z, acR[6]); acR[7] = fmaf(hv, r1.w, acR[7]);
    }

    int node = base + l;
    if (node < N) {
        float4 bl0 = ((const float4*)bl)[w * 2], bl1 = ((const float4*)bl)[w * 2 + 1];
        float4 br0 = ((const float4*)br)[w * 2], br1 = ((const float4*)br)[w * 2 + 1];
        __half2* A2 = (__half2*)A;
        __half2* B2 = (__half2*)B;
        size_t bo = (size_t)node * 32 + w * 4;
        A2[bo + 0] = __floats2half2_rn(acL[0] + bl0.x, acL[1] + bl0.y);
        A2[bo + 1] = __floats2half2_rn(acL[2] + bl0.z, acL[3] + bl0.w);
        A2[bo + 2] = __floats2half2_rn(acL[4] + bl1.x, acL[5] + bl1.y);
        A2[bo + 3] = __floats2half2_rn(acL[6] + bl1.z, acL[7] + bl1.w);
        B2[bo + 0] = __floats2half2_rn(acR[0] + br0.x, acR[1] + br0.y);
        B2[bo + 1] = __floats2half2_rn(acR[2] + br0.z, acR[3] + br0.w);
        B2[bo + 2] = __floats2half2_rn(acR[4] + br1.x, acR[5] + br1.y);
        B2[bo + 3] = __floats2half2_rn(acR[6] + br1.z, acR[7] + br1.w);
    }
}

// fused pool + final linear: one wave per graph; binary-search bounds from sorted batch
__global__ void k_pool_final(const float* __restrict__ C, const float* __restrict__ b2,
                             const int* __restrict__ batch,
                             const float* __restrict__ W3, const float* __restrict__ b3,
                             float* __restrict__ out, int N, int G) {
    int w = (int)((blockIdx.x * (size_t)blockDim.x + threadIdx.x) >> 6);
    int lane = threadIdx.x & 63;
    if (w >= G) return;
    int lo = 0, hi = N;
    while (lo < hi) { int mid = (lo + hi) >> 1; if (batch[mid] < w) lo = mid + 1; else hi = mid; }
    int s0 = lo;
    hi = N;
    while (lo < hi) { int mid = (lo + hi) >> 1; if (batch[mid] < w + 1) lo = mid + 1; else hi = mid; }
    int e0 = lo;

    float acc = -INFINITY;
    int i = s0;
    for (; i + 3 < e0; i += 4) {
        float v0 = C[(size_t)i * HID + lane];
        float v1 = C[(size_t)(i + 1) * HID + lane];
        float v2 = C[(size_t)(i + 2) * HID + lane];
        float v3 = C[(size_t)(i + 3) * HID + lane];
        acc = fmaxf(acc, fmaxf(fmaxf(v0, v1), fmaxf(v2, v3)));
    }
    for (; i < e0; ++i) acc = fmaxf(acc, C[(size_t)i * HID + lane]);
    float v = acc + b2[lane];

    float p0 = v * W3[lane * 2];
    float p1 = v * W3[lane * 2 + 1];
    #pragma unroll
    for (int o = 32; o; o >>= 1) { p0 += __shfl_xor(p0, o); p1 += __shfl_xor(p1, o); }
    if (lane == 0) {
        out[(size_t)w * 2]     = p0 + b3[0];
        out[(size_t)w * 2 + 1] = p1 + b3[1];
    }
}

extern "C" void kernel_launch(void* const* d_in, const int* in_sizes, int n_in,
                              void* d_out, int out_size, void* d_ws, size_t ws_size,
                              hipStream_t stream) {
    const float* x     = (const float*)d_in[0];
    const int*   ei    = (const int*)d_in[1];
    const int*   batch = (const int*)d_in[2];
    const float* Wl1 = (const float*)d_in[3];
    const float* bl1 = (const float*)d_in[4];
    const float* Wr1 = (const float*)d_in[5];
    const float* br1 = (const float*)d_in[6];
    const float* a1  = (const float*)d_in[7];
    const float* b1  = (const float*)d_in[8];
    const float* Wl2 = (const float*)d_in[9];
    const float* bl2 = (const float*)d_in[10];
    const float* Wr2 = (const float*)d_in[11];
    const float* br2 = (const float*)d_in[12];
    const float* a2  = (const float*)d_in[13];
    const float* b2  = (const float*)d_in[14];
    const float* W3  = (const float*)d_in[15];
    const float* b3  = (const float*)d_in[16];

    const int N = in_sizes[0];          // 100000
    const int E = in_sizes[1] / 2;      // 1600000
    const int G = out_size / 2;         // 1000
    const int NB = (N + 255) >> 8;                 // 391 node bins
    const int NBLK = (E + BLK_E - 1) / BLK_E;      // 391 edge blocks

    // ---- workspace layout ----
    float* ws = (float*)d_ws;
    size_t off = 0;
    float*  C  = ws + off; off += (size_t)N * HID;  // sort temporaries + layer-1 fp16 C overlay
    __half* Ah = (__half*)(ws + off); off += (size_t)N * HID / 2;
    __half* Bh = (__half*)(ws + off); off += (size_t)N * HID / 2;
    int*   row_off = (int*)(ws + off); off += N + 1;
    int*   csr_src = (int*)(ws + off); off += E;
    float* deg_in  = ws + off; off += N;
    int*   perm    = (int*)(ws + off); off += N;
    int*   dhist   = (int*)(ws + off); off += 1024;
    int*   bsS  = (int*)(ws + off); off += NB + 1;
    int*   bsD  = (int*)(ws + off); off += NB + 1;
    int*   totS = (int*)(ws + off); off += NB;
    int*   totD = (int*)(ws + off); off += NB;

    unsigned* packD = (unsigned*)C;
    unsigned* packS = packD + E;
    int* histS = (int*)(packS + E);
    int* histD = histS + (size_t)NB * NBLK;
    __half* Chalf = (__half*)C;       // layer-1 output (after packD/packS consumed)

    const int* src  = ei;
    const int* dstp = ei + E;

    const int BT = 256;
    dim3 blk(BT);
    int grid_g8 = (int)(((size_t)N * 8 + BT - 1) / BT);
    int grid_x2 = (N + 63) / 64;

    // ---- CSR build via counting sort (no global atomics) ----
    k_hist2<<<NBLK, 1024, 0, stream>>>(src, dstp, histS, histD, E, NB, NBLK);
    k_binscan<<<2 * NB, 512, 0, stream>>>(histS, histD, totS, totD, NB, NBLK);
    k_binoffset<<<1, 512, 0, stream>>>(totS, totD, bsS, bsD, NB, E, row_off, N);
    k_scatter_bins<<<NBLK, 1024, 0, stream>>>(src, dstp, histS, histD, bsS, bsD,
                                              packS, packD, E, NB, NBLK);
    // fused: CSR finalize + deg_out count + layer-1 transforms
    k_csr_bin_fused<<<NB, 1024, 0, stream>>>(packD, bsD, packS, bsS, row_off, deg_in,
                                             csr_src, x, Wl1, bl1, Wr1, br1, Ah, Bh, N);

    // ---- degree-sorted node permutation (scheduling only) ----
    k_deghist<<<NDB, 1024, 0, stream>>>(deg_in, dhist, N);
    k_degscan<<<1, 1024, 0, stream>>>(dhist);
    k_degscatter<<<NDB, 1024, 0, stream>>>(deg_in, dhist, perm, N);

    // ---- layer 1 (fp16 output) ----
    k_gat_fused<__half, true><<<grid_g8, blk, 0, stream>>>(csr_src, row_off, perm,
                                                           Ah, Bh, a1, b1, Chalf, N);

    // ---- layer 2 ----
    k_xfrm2<<<grid_x2, 512, 0, stream>>>(Chalf, Wl2, bl2, Wr2, br2, Ah, Bh, N);
    k_gat_fused<float, false><<<grid_g8, blk, 0, stream>>>(csr_src, row_off, perm,
                                                           Ah, Bh, a2, b2, C, N);

    // ---- fused pool + final linear ----
    k_pool_final<<<(G * 64 + BT - 1) / BT, blk, 0, stream>>>(C, b2, batch, W3, b3,
                                                             (float*)d_out, N, G);
}